// Round 1
// baseline (867.141 us; speedup 1.0000x reference)
//
#include <hip/hip_runtime.h>
#include <math.h>

// Problem constants
#define KC 1024
#define DD 256
#define NT 65536

// ws layout (in floats)
#define W_COUNTS 0
#define W_DW     1024
#define W_LOSS   (W_DW + KC*DD)          // 263168
#define W_CNORM  263172
#define W_CBT    264196                   // 16B-aligned (264196*4 % 16 == 0)
#define W_IDX    (W_CBT + KC*DD)          // 526340
// total floats used: 526340 + 65536 = 591876  (~2.37 MB)

__device__ __forceinline__ int physrow(int row, int d) {
    // XOR swizzle on 4-row blocks so transposed staging writes spread 8 banks
    // while compute-side ds_read_b128 stays conflict-free.
    return ((((row >> 2) ^ ((d >> 2) & 7)) << 2) | (row & 3));
}

// ---------------------------------------------------------------- prep ----
// cbT[d*1024 + k] = cb[k*256 + d];  cnorm[k] = sum_d cb[k][d]^2
__global__ __launch_bounds__(64) void vq_prep(const float* __restrict__ cb,
                                              float* __restrict__ cbT,
                                              float* __restrict__ cnorm) {
    const int k = blockIdx.x;      // 1024 blocks
    const int l = threadIdx.x;     // 64 lanes
    float4 v = reinterpret_cast<const float4*>(cb)[k * 64 + l];
    cbT[(4 * l + 0) * KC + k] = v.x;
    cbT[(4 * l + 1) * KC + k] = v.y;
    cbT[(4 * l + 2) * KC + k] = v.z;
    cbT[(4 * l + 3) * KC + k] = v.w;
    float s = v.x * v.x + v.y * v.y + v.z * v.z + v.w * v.w;
    #pragma unroll
    for (int off = 32; off; off >>= 1) s += __shfl_down(s, off, 64);
    if (l == 0) cnorm[k] = s;   // cnorm ~8e-5: summation order irrelevant vs ulp(256)
}

// ---------------------------------------------------------------- main ----
// Per block: 128 rows. Full-D fp32 A tile in LDS (swizzled, 128KB) + streamed
// 32x128 B chunks (16KB). 16x16 thread grid, 8x8 register tile.
// Score s = fl(fl(xn+cn) - fl(2*dot))  -- replicates reference rounding.
__global__ __launch_bounds__(256) void vq_main(const float* __restrict__ X,
                                               const float* __restrict__ cbT,
                                               const float* __restrict__ cnorm,
                                               float* __restrict__ counts,
                                               int* __restrict__ idxw,
                                               float* __restrict__ idxf) {
    extern __shared__ float smem[];
    float* As = smem;              // 256*128 = 32768 floats
    float* Bs = smem + 32768;      // 32*128  = 4096  floats
    float* xn = smem + 36992 - 128;// 128 floats

    const int t  = threadIdx.x;
    const int tx = t & 15;
    const int ty = t >> 4;
    const int row0 = blockIdx.x * 128;

    // ---- stage A (transposed + swizzled), coalesced global float4 loads ----
    const float4* X4 = reinterpret_cast<const float4*>(X);
    #pragma unroll 4
    for (int p = 0; p < 32; ++p) {
        int fid = p * 256 + t;          // 0..8191
        int row = fid >> 6;             // 0..127
        int d4  = fid & 63;
        float4 v = X4[(size_t)row0 * 64 + (size_t)row * 64 + d4];
        int d = d4 << 2;
        int ph = physrow(row, d);
        As[(d + 0) * 128 + ph] = v.x;
        As[(d + 1) * 128 + ph] = v.y;
        As[(d + 2) * 128 + ph] = v.z;
        As[(d + 3) * 128 + ph] = v.w;
    }
    __syncthreads();

    // ---- xn[row]: numpy pairwise tree (128+128, 8-way unroll), NO contraction ----
    if (t < 128) {
        #pragma clang fp contract(off)
        float tot = 0.f;
        #pragma unroll
        for (int h = 0; h < 2; ++h) {
            float r[8];
            #pragma unroll
            for (int j = 0; j < 8; ++j) {
                int d = h * 128 + j;
                float a = As[d * 128 + physrow(t, d)];
                float p = a * a;
                r[j] = p;
            }
            for (int i = 1; i < 16; ++i) {
                #pragma unroll
                for (int j = 0; j < 8; ++j) {
                    int d = h * 128 + i * 8 + j;
                    float a = As[d * 128 + physrow(t, d)];
                    float p = a * a;
                    r[j] = r[j] + p;
                }
            }
            float s = ((r[0] + r[1]) + (r[2] + r[3])) + ((r[4] + r[5]) + (r[6] + r[7]));
            tot = tot + s;
        }
        xn[t] = tot;
    }

    float bestV[8];
    int   bestI[8];
    #pragma unroll
    for (int i = 0; i < 8; ++i) { bestV[i] = 3.4e38f; bestI[i] = 0; }

    const float4* cbT4 = reinterpret_cast<const float4*>(cbT);

    #pragma unroll 1
    for (int ct = 0; ct < 8; ++ct) {
        float acc[8][8];
        #pragma unroll
        for (int i = 0; i < 8; ++i)
            #pragma unroll
            for (int j = 0; j < 8; ++j) acc[i][j] = 0.f;

        #pragma unroll 1
        for (int dk = 0; dk < 8; ++dk) {
            __syncthreads();   // protect Bs from previous iteration's readers
            // stage B chunk: Bs[dd*128 + c] = cbT[(dk*32+dd)*1024 + ct*128 + c]
            #pragma unroll
            for (int it = 0; it < 4; ++it) {
                int fid = it * 256 + t;      // 0..1023 float4s
                int dd  = fid >> 5;
                int c4  = fid & 31;
                float4 v = cbT4[(size_t)(dk * 32 + dd) * 256 + ct * 32 + c4];
                reinterpret_cast<float4*>(Bs)[dd * 32 + c4] = v;
            }
            __syncthreads();

            #pragma unroll 8
            for (int dd = 0; dd < 32; ++dd) {
                const int d  = dk * 32 + dd;
                const int sw = (dd >> 2) & 7;          // == (d>>2)&7 (dk*32 ≡ 0 mod 32)
                const int ar = ((ty ^ sw) << 2);
                const float4 a0 = *reinterpret_cast<const float4*>(&As[d * 128 + ar]);
                const float4 a1 = *reinterpret_cast<const float4*>(&As[d * 128 + ar + 64]);
                const float4 b0 = *reinterpret_cast<const float4*>(&Bs[dd * 128 + (tx << 2)]);
                const float4 b1 = *reinterpret_cast<const float4*>(&Bs[dd * 128 + (tx << 2) + 64]);
                const float av[8] = {a0.x, a0.y, a0.z, a0.w, a1.x, a1.y, a1.z, a1.w};
                const float bv[8] = {b0.x, b0.y, b0.z, b0.w, b1.x, b1.y, b1.z, b1.w};
                #pragma unroll
                for (int i = 0; i < 8; ++i)
                    #pragma unroll
                    for (int j = 0; j < 8; ++j)
                        acc[i][j] = fmaf(av[i], bv[j], acc[i][j]);
            }
        }

        // ---- tile epilogue: scores + running argmin (reference rounding) ----
        {
            #pragma clang fp contract(off)
            float cnv[8];
            int   gcl[8];
            #pragma unroll
            for (int j = 0; j < 8; ++j) {
                int cl = (j < 4) ? (tx * 4 + j) : (64 + tx * 4 + (j - 4));
                gcl[j] = ct * 128 + cl;
                cnv[j] = cnorm[gcl[j]];
            }
            #pragma unroll
            for (int i = 0; i < 8; ++i) {
                int rowl = (i < 4) ? (ty * 4 + i) : (64 + ty * 4 + (i - 4));
                float xr = xn[rowl];
                #pragma unroll
                for (int j = 0; j < 8; ++j) {
                    float t1 = xr + cnv[j];          // fl(xn + cn)
                    float t2 = 2.0f * acc[i][j];     // exact
                    float s  = t1 - t2;              // fl(sub)
                    if (s < bestV[i]) { bestV[i] = s; bestI[i] = gcl[j]; }
                }
            }
        }
    }

    // ---- cross-tx argmin reduction via LDS (reuse Bs) ----
    __syncthreads();
    float2* red = reinterpret_cast<float2*>(Bs);     // 128 rows x 16 tx
    #pragma unroll
    for (int i = 0; i < 8; ++i) {
        int rowl = (i < 4) ? (ty * 4 + i) : (64 + ty * 4 + (i - 4));
        red[rowl * 16 + tx] = make_float2(bestV[i], (float)bestI[i]);
    }
    __syncthreads();
    if (t < 128) {
        float bv = 3.4e38f, bi = 0.f;
        #pragma unroll
        for (int x = 0; x < 16; ++x) {
            float2 e = red[t * 16 + x];
            if (e.x < bv || (e.x == bv && e.y < bi)) { bv = e.x; bi = e.y; }
        }
        int n = row0 + t;
        idxf[n] = bi;                 // indices as float (d_out is float32)
        idxw[n] = (int)bi;
        unsafeAtomicAdd(&counts[(int)bi], 1.0f);
    }
}

// -------------------------------------------------------------- gather ----
// quantized_st, dw scatter, commitment-loss partial sums.
__global__ __launch_bounds__(256) void vq_gather(const float* __restrict__ X,
                                                 const float* __restrict__ CB,
                                                 const int* __restrict__ idxw,
                                                 float* __restrict__ out0,
                                                 float* __restrict__ dw,
                                                 float* __restrict__ loss) {
    const int t    = threadIdx.x;
    const int wave = (blockIdx.x * 256 + t) >> 6;   // 0..1023
    const int lane = t & 63;
    const float4* X4 = reinterpret_cast<const float4*>(X);
    const float4* C4 = reinterpret_cast<const float4*>(CB);
    float4* O4 = reinterpret_cast<float4*>(out0);
    float lsum = 0.f;
    for (int r = 0; r < 64; ++r) {
        const int n = wave * 64 + r;
        const int idx = idxw[n];
        float4 x = X4[n * 64 + lane];
        float4 c = C4[idx * 64 + lane];
        float d0 = c.x - x.x, d1 = c.y - x.y, d2 = c.z - x.z, d3 = c.w - x.w;
        float4 q;
        q.x = x.x + d0; q.y = x.y + d1; q.z = x.z + d2; q.w = x.w + d3;
        O4[n * 64 + lane] = q;
        lsum += d0 * d0 + d1 * d1 + d2 * d2 + d3 * d3;
        int base = idx * 256 + lane * 4;
        unsafeAtomicAdd(&dw[base + 0], x.x);
        unsafeAtomicAdd(&dw[base + 1], x.y);
        unsafeAtomicAdd(&dw[base + 2], x.z);
        unsafeAtomicAdd(&dw[base + 3], x.w);
    }
    #pragma unroll
    for (int off = 32; off; off >>= 1) lsum += __shfl_down(lsum, off, 64);
    if (lane == 0) unsafeAtomicAdd(loss, lsum);
}

// ---------------------------------------------------------- finalize 1 ----
__global__ void vq_fin1(const float* __restrict__ counts,
                        const float* __restrict__ ecs,
                        const float* __restrict__ loss,
                        float* __restrict__ out1, float* __restrict__ out3,
                        float* __restrict__ out4) {
    __shared__ float sd[1024];
    const int t = threadIdx.x;
    float c   = counts[t];
    float pre = 0.99f * ecs[t] + 0.01f * c;
    sd[t] = pre; __syncthreads();
    for (int off = 512; off; off >>= 1) { if (t < off) sd[t] += sd[t + off]; __syncthreads(); }
    float n_total = sd[0];
    __syncthreads();
    float avg = c * (1.0f / 65536.0f);
    float ent = avg * logf(avg + 1e-10f);
    sd[t] = ent; __syncthreads();
    for (int off = 512; off; off >>= 1) { if (t < off) sd[t] += sd[t + off]; __syncthreads(); }
    float entsum = sd[0];
    float ncs = (pre + 1e-5f) / (n_total + 1024.0f * 1e-5f) * n_total;
    out4[t] = ncs;
    if (t == 0) {
        out1[0] = 0.25f * (loss[0] / 16777216.0f);
        out3[0] = expf(-entsum);
    }
}

// ---------------------------------------------------------- finalize 2 ----
__global__ __launch_bounds__(256) void vq_fin2(const float* __restrict__ emw,
                                               const float* __restrict__ dwv,
                                               const float* __restrict__ ncs,
                                               float* __restrict__ out5,
                                               float* __restrict__ out6) {
    int i = blockIdx.x * 256 + threadIdx.x;   // 0..262143
    float e = 0.99f * emw[i] + 0.01f * dwv[i];
    out5[i] = e;
    out6[i] = e / ncs[i >> 8];
}

// ---------------------------------------------------------------- launch --
extern "C" void kernel_launch(void* const* d_in, const int* in_sizes, int n_in,
                              void* d_out, int out_size, void* d_ws, size_t ws_size,
                              hipStream_t stream) {
    const float* X   = (const float*)d_in[0];   // [65536,256]
    const float* CB  = (const float*)d_in[1];   // [1024,256]
    const float* ECS = (const float*)d_in[2];   // [1024]
    const float* EMW = (const float*)d_in[3];   // [1024,256]

    float* out0 = (float*)d_out;                // quantized_st  [N*D]
    float* out1 = out0 + (size_t)NT * DD;       // vq_loss       [1]
    float* out2 = out1 + 1;                     // indices(f32)  [N]
    float* out3 = out2 + NT;                    // perplexity    [1]
    float* out4 = out3 + 1;                     // new_cs        [K]
    float* out5 = out4 + KC;                    // new_ema_w     [K*D]
    float* out6 = out5 + (size_t)KC * DD;       // new_weight    [K*D]

    float* ws     = (float*)d_ws;
    float* counts = ws + W_COUNTS;
    float* dw     = ws + W_DW;
    float* loss   = ws + W_LOSS;
    float* cnorm  = ws + W_CNORM;
    float* cbT    = ws + W_CBT;
    int*   idxw   = (int*)(ws + W_IDX);

    // zero counts + dw + loss (ws is poisoned 0xAA before every call)
    hipMemsetAsync(ws, 0, (size_t)(W_LOSS + 1) * sizeof(float), stream);

    vq_prep<<<KC, 64, 0, stream>>>(CB, cbT, cnorm);
    vq_main<<<NT / 128, 256, 36992 * sizeof(float), stream>>>(X, cbT, cnorm, counts, idxw, out2);
    vq_gather<<<256, 256, 0, stream>>>(X, CB, idxw, out0, dw, loss);
    vq_fin1<<<1, 1024, 0, stream>>>(counts, ECS, loss, out1, out3, out4);
    vq_fin2<<<KC * DD / 256, 256, 0, stream>>>(EMW, dw, out4, out5, out6);
}